// Round 1
// baseline (352.669 us; speedup 1.0000x reference)
//
#include <hip/hip_runtime.h>
#include <math.h>

#define NATOMS   1025
#define GSTRIDE  1040               // padded row stride (floats); cols 1025..1039 are zero pad
#define GELEMS   (1025*GSTRIDE)     // 1,066,000 floats per Gram buffer
#define NNZ      32
#define NBATCH   64
#define REGL     0.0067153485f      // softplus(-5) in fp32

// ---------------------------------------------------------------------------
// Gram: Gp[bz] = D[kr]^T D[kr]  (D = [X0 | ones], 1024 x 1025, zero-padded to 1040)
// tile 128x128, 8x8 per thread, 256 threads, split-K via blockIdx.z
// ---------------------------------------------------------------------------
__global__ __launch_bounds__(256)
void gram_kernel(const float* __restrict__ X0, float* __restrict__ Gout, int kLen) {
    __shared__ float As[32][128];
    __shared__ float Bs[32][128];
    const int bx = blockIdx.x, by = blockIdx.y, bz = blockIdx.z;
    const int a0 = bx * 128, b0 = by * 128;
    float* __restrict__ Gp = Gout + (size_t)bz * GELEMS;
    const int tid = threadIdx.x;
    const int tx = tid & 15;         // b-direction (two 4-col groups)
    const int ty = tid >> 4;         // a-direction (8 contiguous cols)
    const int lr = tid >> 5;         // load row 0..7
    const int lc = (tid & 31) * 4;   // load col 0..124
    const bool aIn = (a0 + 128) <= 1024;
    const bool bIn = (b0 + 128) <= 1024;

    float acc[8][8];
#pragma unroll
    for (int m = 0; m < 8; ++m)
#pragma unroll
        for (int n = 0; n < 8; ++n) acc[m][n] = 0.0f;

    const int kBase = bz * kLen;
    for (int kc = 0; kc < kLen; kc += 32) {
#pragma unroll
        for (int rr = 0; rr < 4; ++rr) {
            const int r = lr + rr * 8;
            const int l = kBase + kc + r;
            if (aIn) {
                *(float4*)&As[r][lc] = *(const float4*)&X0[(size_t)l * 1024 + a0 + lc];
            } else {
#pragma unroll
                for (int k = 0; k < 4; ++k) {
                    const int col = a0 + lc + k;
                    As[r][lc + k] = (col < 1024) ? X0[(size_t)l * 1024 + col]
                                                 : (col == 1024 ? 1.0f : 0.0f);
                }
            }
            if (bIn) {
                *(float4*)&Bs[r][lc] = *(const float4*)&X0[(size_t)l * 1024 + b0 + lc];
            } else {
#pragma unroll
                for (int k = 0; k < 4; ++k) {
                    const int col = b0 + lc + k;
                    Bs[r][lc + k] = (col < 1024) ? X0[(size_t)l * 1024 + col]
                                                 : (col == 1024 ? 1.0f : 0.0f);
                }
            }
        }
        __syncthreads();
#pragma unroll 8
        for (int l = 0; l < 32; ++l) {
            float4 a01 = *(const float4*)&As[l][ty * 8];
            float4 a23 = *(const float4*)&As[l][ty * 8 + 4];
            float4 bA  = *(const float4*)&Bs[l][tx * 4];
            float4 bB  = *(const float4*)&Bs[l][64 + tx * 4];
            float am[8] = {a01.x, a01.y, a01.z, a01.w, a23.x, a23.y, a23.z, a23.w};
            float bn[8] = {bA.x, bA.y, bA.z, bA.w, bB.x, bB.y, bB.z, bB.w};
#pragma unroll
            for (int m = 0; m < 8; ++m)
#pragma unroll
                for (int n = 0; n < 8; ++n)
                    acc[m][n] += am[m] * bn[n];
        }
        __syncthreads();
    }

#pragma unroll
    for (int m = 0; m < 8; ++m) {
        const int a = a0 + ty * 8 + m;
        if (a >= NATOMS) continue;
        const int bAc = b0 + tx * 4;
        const int bBc = b0 + 64 + tx * 4;
        if (bAc < GSTRIDE) {
            *(float4*)&Gp[(size_t)a * GSTRIDE + bAc] =
                make_float4(acc[m][0], acc[m][1], acc[m][2], acc[m][3]);
        }
        if (bBc < GSTRIDE) {
            *(float4*)&Gp[(size_t)a * GSTRIDE + bBc] =
                make_float4(acc[m][4], acc[m][5], acc[m][6], acc[m][7]);
        }
    }
}

__global__ __launch_bounds__(256)
void combine_kernel(const float* __restrict__ Gp, float* __restrict__ G) {
    const int gid = blockIdx.x * 256 + threadIdx.x;
    if (gid < GELEMS / 4) {
        const float4* p0 = (const float4*)Gp;
        const float4* p1 = (const float4*)(Gp + (size_t)GELEMS);
        const float4* p2 = (const float4*)(Gp + 2 * (size_t)GELEMS);
        const float4* p3 = (const float4*)(Gp + 3 * (size_t)GELEMS);
        float4 a = p0[gid], b = p1[gid], c = p2[gid], d = p3[gid];
        ((float4*)G)[gid] = make_float4(a.x + b.x + c.x + d.x, a.y + b.y + c.y + d.y,
                                        a.z + b.z + c.z + d.z, a.w + b.w + c.w + d.w);
    }
}

// ---------------------------------------------------------------------------
// projy: PY[b][a] = sum_l y[b][l] * D[l][a]     (64 x 1025, padded to 1040)
// ---------------------------------------------------------------------------
__global__ __launch_bounds__(256)
void projy_kernel(const float* __restrict__ X0, const float* __restrict__ y,
                  float* __restrict__ PY) {
    __shared__ float Ds[32][64];
    __shared__ float Ys[32][68];     // padded: conflict-light writes, 16B-aligned rows
    const int a0 = blockIdx.x * 64;
    const int tid = threadIdx.x;
    const int tx = tid & 15;   // atom dir (4 each)
    const int ty = tid >> 4;   // batch dir (4 each)
    const bool aIn = (a0 + 64) <= 1024;

    float acc[4][4] = {};

    for (int kc = 0; kc < 1024; kc += 32) {
        {
            const int r  = tid >> 4;         // 0..15
            const int c4 = (tid & 15) * 4;   // 0..60
#pragma unroll
            for (int rr = 0; rr < 2; ++rr) {
                const int row = r + rr * 16;
                const int l = kc + row;
                if (aIn) {
                    *(float4*)&Ds[row][c4] = *(const float4*)&X0[(size_t)l * 1024 + a0 + c4];
                } else {
#pragma unroll
                    for (int k = 0; k < 4; ++k) {
                        const int col = a0 + c4 + k;
                        Ds[row][c4 + k] = (col < 1024) ? X0[(size_t)l * 1024 + col]
                                                       : (col == 1024 ? 1.0f : 0.0f);
                    }
                }
            }
        }
        for (int e = tid; e < 2048; e += 256) {
            const int l = e & 31, bb = e >> 5;
            Ys[l][bb] = y[(size_t)bb * 1024 + kc + l];
        }
        __syncthreads();
#pragma unroll 8
        for (int l = 0; l < 32; ++l) {
            float4 yv = *(const float4*)&Ys[l][ty * 4];
            float4 dv = *(const float4*)&Ds[l][tx * 4];
            float ym[4] = {yv.x, yv.y, yv.z, yv.w};
            float dn[4] = {dv.x, dv.y, dv.z, dv.w};
#pragma unroll
            for (int m = 0; m < 4; ++m)
#pragma unroll
                for (int n = 0; n < 4; ++n)
                    acc[m][n] += ym[m] * dn[n];
        }
        __syncthreads();
    }
#pragma unroll
    for (int m = 0; m < 4; ++m) {
        const int bb = ty * 4 + m;
        const int a = a0 + tx * 4;
        if (a < GSTRIDE) {
            *(float4*)&PY[(size_t)bb * GSTRIDE + a] =
                make_float4(acc[m][0], acc[m][1], acc[m][2], acc[m][3]);
        }
    }
}

// ---------------------------------------------------------------------------
// omp: one workgroup per batch. 32 iterations of:
//   proj[a] = PY0[a] - sum_j w[j]*G[sel_j][a];  sel_i = argmax |proj| (first-index ties)
//   ridge solve via bordered inverse update: Ainv grows by one row/col per iter
// ---------------------------------------------------------------------------
__global__ __launch_bounds__(256)
void omp_kernel(const float* __restrict__ G, const float* __restrict__ PY,
                int* __restrict__ idxOut, float* __restrict__ wOut) {
    __shared__ float4 py4[260];          // 1040 floats: original y@D row (never modified)
    __shared__ float Ainv[32][33];       // padded stride: conflict-free matvec
    __shared__ float wv[32], rhs[32], bvv[32], uv[32];
    __shared__ int   selIdx[32];
    __shared__ float redV[4];
    __shared__ int   redI[4];
    __shared__ float sc_dinv, sc_c;

    const int b = blockIdx.x, tid = threadIdx.x;
    const int lane = tid & 63, wid = tid >> 6;

    const float4* pyg = (const float4*)(PY + (size_t)b * GSTRIDE);
    for (int u = tid; u < 260; u += 256) py4[u] = pyg[u];
    __syncthreads();
    const float* pys = (const float*)py4;

    for (int i = 0; i < NNZ; ++i) {
        // ---- proj + local abs-argmax (atoms 1025..1039 are zero pad, never win)
        float best = -1.0f; int bidx = 0;
        for (int u = tid; u < 260; u += 256) {
            float4 p = py4[u];
#pragma unroll 4
            for (int j = 0; j < i; ++j) {
                const float4 g = *(const float4*)(G + (size_t)selIdx[j] * GSTRIDE + 4 * u);
                const float wj = wv[j];
                p.x -= wj * g.x; p.y -= wj * g.y; p.z -= wj * g.z; p.w -= wj * g.w;
            }
            float pv[4] = {fabsf(p.x), fabsf(p.y), fabsf(p.z), fabsf(p.w)};
#pragma unroll
            for (int k = 0; k < 4; ++k) {
                if (pv[k] > best) { best = pv[k]; bidx = 4 * u + k; }
            }
        }
        // ---- wave then block argmax reduce (ties -> lower index, matches jnp.argmax)
        for (int off = 32; off; off >>= 1) {
            float ov = __shfl_xor(best, off);
            int   oi = __shfl_xor(bidx, off);
            if (ov > best || (ov == best && oi < bidx)) { best = ov; bidx = oi; }
        }
        if (lane == 0) { redV[wid] = best; redI[wid] = bidx; }
        __syncthreads();
        if (tid == 0) {
            float bv_ = redV[0]; int bi_ = redI[0];
            for (int q = 1; q < 4; ++q) {
                if (redV[q] > bv_ || (redV[q] == bv_ && redI[q] < bi_)) {
                    bv_ = redV[q]; bi_ = redI[q];
                }
            }
            selIdx[i] = bi_;
            rhs[i] = pys[bi_];           // DTy entry = original proj_y at selected atom
        }
        __syncthreads();
        const int sel = selIdx[i];

        // ---- gather small-Gram border: b[j] = G[sel][sel_j], c = G[sel][sel]
        if (tid < i) bvv[tid] = G[(size_t)sel * GSTRIDE + selIdx[tid]];
        if (tid == i) sc_c = G[(size_t)sel * GSTRIDE + sel];
        __syncthreads();

        // ---- wave 0: u = Ainv*b ; d = c + reg - b.u
        if (wid == 0) {
            float uj = 0.0f;
            if (lane < i) {
                for (int m = 0; m < i; ++m) uj += Ainv[lane][m] * bvv[m];
                uv[lane] = uj;
            }
            float t = (lane < i) ? bvv[lane] * uj : 0.0f;
            for (int off = 32; off; off >>= 1) t += __shfl_xor(t, off);
            if (lane == 0) sc_dinv = 1.0f / (sc_c + REGL - t);
        }
        __syncthreads();
        const float dinv = sc_dinv;

        // ---- bordered inverse update
        for (int e = tid; e < i * i; e += 256) {
            const int j = e / i, k = e - j * i;
            Ainv[j][k] += uv[j] * uv[k] * dinv;
        }
        if (tid < i) {
            const float v = -uv[tid] * dinv;
            Ainv[i][tid] = v;
            Ainv[tid][i] = v;
        }
        if (tid == 0) Ainv[i][i] = dinv;
        __syncthreads();

        // ---- w = Ainv * rhs (size i+1)
        if (wid == 0 && lane <= i) {
            float s = 0.0f;
            for (int k = 0; k <= i; ++k) s += Ainv[lane][k] * rhs[k];
            wv[lane] = s;
        }
        __syncthreads();
    }

    if (tid < NNZ) {
        idxOut[b * NNZ + tid] = selIdx[tid];
        wOut[b * NNZ + tid] = wv[tid];
    }
}

// ---------------------------------------------------------------------------
// recon: out[b][l] = sum_a X[b][l][a]*W[b][a] + W[b][1024]
// W built dense in LDS with sequential last-wins scatter (matches .at[].set)
// ---------------------------------------------------------------------------
__global__ __launch_bounds__(256)
void recon_kernel(const float* __restrict__ X, const int* __restrict__ idxIn,
                  const float* __restrict__ wIn, float* __restrict__ out) {
    __shared__ float4 Wd4[260];          // 1040 floats
    const int b = blockIdx.x >> 3, chunk = blockIdx.x & 7;
    const int tid = threadIdx.x, lane = tid & 63, wid = tid >> 6;
    float* Wd = (float*)Wd4;
    for (int u = tid; u < 1040; u += 256) Wd[u] = 0.0f;
    __syncthreads();
    if (tid == 0) {
#pragma unroll
        for (int i = 0; i < NNZ; ++i) Wd[idxIn[b * NNZ + i]] = wIn[b * NNZ + i];
    }
    __syncthreads();
    const float wOne = Wd[1024];
    const float* Xb = X + (size_t)b * 1024 * 1024;

    for (int rr = wid; rr < 128; rr += 4) {
        const int r = chunk * 128 + rr;
        const float4* xr = (const float4*)(Xb + (size_t)r * 1024);
        float acc = 0.0f;
#pragma unroll
        for (int q = 0; q < 4; ++q) {
            float4 x = xr[q * 64 + lane];
            float4 w = Wd4[q * 64 + lane];
            acc += x.x * w.x + x.y * w.y + x.z * w.z + x.w * w.w;
        }
        for (int off = 32; off; off >>= 1) acc += __shfl_xor(acc, off);
        if (lane == 0) out[(size_t)b * 1024 + r] = acc + wOne;
    }
}

// ---------------------------------------------------------------------------
extern "C" void kernel_launch(void* const* d_in, const int* in_sizes, int n_in,
                              void* d_out, int out_size, void* d_ws, size_t ws_size,
                              hipStream_t stream) {
    const float* X = (const float*)d_in[0];
    const float* y = (const float*)d_in[1];
    float* out = (float*)d_out;
    float* ws = (float*)d_ws;

    // workspace layout (floats):
    //   split-K=4:  [4 x GELEMS partials][GELEMS G][64*GSTRIDE PY][w 2048][idx 2048]
    //   fallback:   [GELEMS G][64*GSTRIDE PY][w 2048][idx 2048]
    const size_t need4 = ((size_t)GELEMS * 5 + 64 * GSTRIDE + NBATCH * NNZ * 2 + 64) * sizeof(float);
    const bool split4 = (ws_size >= need4);

    float* G;
    if (split4) {
        float* Gp = ws;
        G = ws + (size_t)GELEMS * 4;
        gram_kernel<<<dim3(9, 9, 4), 256, 0, stream>>>(X, Gp, 256);
        combine_kernel<<<(GELEMS / 4 + 255) / 256, 256, 0, stream>>>(Gp, G);
    } else {
        G = ws;
        gram_kernel<<<dim3(9, 9, 1), 256, 0, stream>>>(X, G, 1024);
    }
    float* PY = G + (size_t)GELEMS;
    float* wOut = PY + (size_t)64 * GSTRIDE;
    int* idxOut = (int*)(wOut + NBATCH * NNZ);

    projy_kernel<<<17, 256, 0, stream>>>(X, y, PY);
    omp_kernel<<<NBATCH, 256, 0, stream>>>(G, PY, idxOut, wOut);
    recon_kernel<<<NBATCH * 8, 256, 0, stream>>>(X, idxOut, wOut, out);
}

// Round 2
// 285.735 us; speedup vs baseline: 1.2343x; 1.2343x over previous
//
#include <hip/hip_runtime.h>
#include <math.h>

#define NATOMS   1025
#define GSTRIDE  1040               // padded row stride (floats); cols 1025..1039 are zero pad
#define GELEMS   (1025*GSTRIDE)     // 1,066,000 floats per Gram buffer
#define NNZ      32
#define NBATCH   64
#define REGL     0.0067153485f      // softplus(-5) in fp32

// ---------------------------------------------------------------------------
// Gram: Gp[bz] = D[kr]^T D[kr]  (D = [X0 | ones], 1024 x 1025, zero-padded to 1040)
// tile 128x128, 8x8 per thread, 256 threads, split-K via blockIdx.z
// ---------------------------------------------------------------------------
__global__ __launch_bounds__(256)
void gram_kernel(const float* __restrict__ X0, float* __restrict__ Gout, int kLen) {
    __shared__ float As[32][128];
    __shared__ float Bs[32][128];
    const int bx = blockIdx.x, by = blockIdx.y, bz = blockIdx.z;
    const int a0 = bx * 128, b0 = by * 128;
    float* __restrict__ Gp = Gout + (size_t)bz * GELEMS;
    const int tid = threadIdx.x;
    const int tx = tid & 15;         // b-direction (two 4-col groups)
    const int ty = tid >> 4;         // a-direction (8 contiguous cols)
    const int lr = tid >> 5;         // load row 0..7
    const int lc = (tid & 31) * 4;   // load col 0..124
    const bool aIn = (a0 + 128) <= 1024;
    const bool bIn = (b0 + 128) <= 1024;

    float acc[8][8];
#pragma unroll
    for (int m = 0; m < 8; ++m)
#pragma unroll
        for (int n = 0; n < 8; ++n) acc[m][n] = 0.0f;

    const int kBase = bz * kLen;
    for (int kc = 0; kc < kLen; kc += 32) {
#pragma unroll
        for (int rr = 0; rr < 4; ++rr) {
            const int r = lr + rr * 8;
            const int l = kBase + kc + r;
            if (aIn) {
                *(float4*)&As[r][lc] = *(const float4*)&X0[(size_t)l * 1024 + a0 + lc];
            } else {
#pragma unroll
                for (int k = 0; k < 4; ++k) {
                    const int col = a0 + lc + k;
                    As[r][lc + k] = (col < 1024) ? X0[(size_t)l * 1024 + col]
                                                 : (col == 1024 ? 1.0f : 0.0f);
                }
            }
            if (bIn) {
                *(float4*)&Bs[r][lc] = *(const float4*)&X0[(size_t)l * 1024 + b0 + lc];
            } else {
#pragma unroll
                for (int k = 0; k < 4; ++k) {
                    const int col = b0 + lc + k;
                    Bs[r][lc + k] = (col < 1024) ? X0[(size_t)l * 1024 + col]
                                                 : (col == 1024 ? 1.0f : 0.0f);
                }
            }
        }
        __syncthreads();
#pragma unroll 8
        for (int l = 0; l < 32; ++l) {
            float4 a01 = *(const float4*)&As[l][ty * 8];
            float4 a23 = *(const float4*)&As[l][ty * 8 + 4];
            float4 bA  = *(const float4*)&Bs[l][tx * 4];
            float4 bB  = *(const float4*)&Bs[l][64 + tx * 4];
            float am[8] = {a01.x, a01.y, a01.z, a01.w, a23.x, a23.y, a23.z, a23.w};
            float bn[8] = {bA.x, bA.y, bA.z, bA.w, bB.x, bB.y, bB.z, bB.w};
#pragma unroll
            for (int m = 0; m < 8; ++m)
#pragma unroll
                for (int n = 0; n < 8; ++n)
                    acc[m][n] += am[m] * bn[n];
        }
        __syncthreads();
    }

#pragma unroll
    for (int m = 0; m < 8; ++m) {
        const int a = a0 + ty * 8 + m;
        if (a >= NATOMS) continue;
        const int bAc = b0 + tx * 4;
        const int bBc = b0 + 64 + tx * 4;
        if (bAc < GSTRIDE) {
            *(float4*)&Gp[(size_t)a * GSTRIDE + bAc] =
                make_float4(acc[m][0], acc[m][1], acc[m][2], acc[m][3]);
        }
        if (bBc < GSTRIDE) {
            *(float4*)&Gp[(size_t)a * GSTRIDE + bBc] =
                make_float4(acc[m][4], acc[m][5], acc[m][6], acc[m][7]);
        }
    }
}

__global__ __launch_bounds__(256)
void combine_kernel(const float* __restrict__ Gp, float* __restrict__ G) {
    const int gid = blockIdx.x * 256 + threadIdx.x;
    if (gid < GELEMS / 4) {
        const float4* p0 = (const float4*)Gp;
        const float4* p1 = (const float4*)(Gp + (size_t)GELEMS);
        const float4* p2 = (const float4*)(Gp + 2 * (size_t)GELEMS);
        const float4* p3 = (const float4*)(Gp + 3 * (size_t)GELEMS);
        float4 a = p0[gid], b = p1[gid], c = p2[gid], d = p3[gid];
        ((float4*)G)[gid] = make_float4(a.x + b.x + c.x + d.x, a.y + b.y + c.y + d.y,
                                        a.z + b.z + c.z + d.z, a.w + b.w + c.w + d.w);
    }
}

// ---------------------------------------------------------------------------
// projy: PY[b][a] = sum_l y[b][l] * D[l][a]   grid (17, 4): 64-atom x 16-batch tiles
// ---------------------------------------------------------------------------
__global__ __launch_bounds__(256)
void projy_kernel(const float* __restrict__ X0, const float* __restrict__ y,
                  float* __restrict__ PY) {
    __shared__ float Ds[32][64];
    __shared__ float Ys[32][17];     // 16 batches + pad
    const int a0 = blockIdx.x * 64;
    const int b0 = blockIdx.y * 16;
    const int tid = threadIdx.x;
    const int tx = tid & 15;   // atom dir (4 each)
    const int ty = tid >> 4;   // batch (1 each, 16 total)
    const bool aIn = (a0 + 64) <= 1024;

    float acc[4] = {0.0f, 0.0f, 0.0f, 0.0f};

    for (int kc = 0; kc < 1024; kc += 32) {
        {
            const int r  = tid >> 4;         // 0..15
            const int c4 = (tid & 15) * 4;   // 0..60
#pragma unroll
            for (int rr = 0; rr < 2; ++rr) {
                const int row = r + rr * 16;
                const int l = kc + row;
                if (aIn) {
                    *(float4*)&Ds[row][c4] = *(const float4*)&X0[(size_t)l * 1024 + a0 + c4];
                } else {
#pragma unroll
                    for (int k = 0; k < 4; ++k) {
                        const int col = a0 + c4 + k;
                        Ds[row][c4 + k] = (col < 1024) ? X0[(size_t)l * 1024 + col]
                                                       : (col == 1024 ? 1.0f : 0.0f);
                    }
                }
            }
        }
        for (int e = tid; e < 512; e += 256) {
            const int l = e & 31, bb = e >> 5;
            Ys[l][bb] = y[(size_t)(b0 + bb) * 1024 + kc + l];
        }
        __syncthreads();
#pragma unroll 8
        for (int l = 0; l < 32; ++l) {
            const float yv = Ys[l][ty];
            float4 dv = *(const float4*)&Ds[l][tx * 4];
            acc[0] += yv * dv.x; acc[1] += yv * dv.y;
            acc[2] += yv * dv.z; acc[3] += yv * dv.w;
        }
        __syncthreads();
    }
    const int a = a0 + tx * 4;
    if (a < GSTRIDE) {
        *(float4*)&PY[(size_t)(b0 + ty) * GSTRIDE + a] =
            make_float4(acc[0], acc[1], acc[2], acc[3]);
    }
}

// ---------------------------------------------------------------------------
// omp: one workgroup per batch. LDS-cached selected Gram rows (~130KB).
// Per iteration (4 barriers):
//   A: proj[a] = PY0[a] - sum_j w[j]*rowsLds[j][a]; abs-argmax (first-index ties)
//   B: stage G[sel] row -> LDS; gather border b[], c, rhs
//   C: u = Ainv*b; dinv = 1/(c+reg-b.u); beta = dinv*(rhs_i - u.r_old)
//   D: w = [w_old - u*beta; beta]; bordered Ainv update
// ---------------------------------------------------------------------------
__global__ __launch_bounds__(256)
void omp_kernel(const float* __restrict__ G, const float* __restrict__ PY,
                int* __restrict__ idxOut, float* __restrict__ wOut) {
    __shared__ float rowsLds[NNZ][GSTRIDE];   // 133,120 B: selected Gram rows
    __shared__ float4 py4[260];               // 1040 floats: original y@D row
    __shared__ float Ainv[32][33];            // padded stride: conflict-free
    __shared__ float wv[32], rhs[32], bvv[32], uv[32];
    __shared__ int   selIdx[32];
    __shared__ float redV[4];
    __shared__ int   redI[4];
    __shared__ float sc_dinv, sc_beta, sc_c;

    const int b = blockIdx.x, tid = threadIdx.x;
    const int lane = tid & 63, wid = tid >> 6;

    const float4* pyg = (const float4*)(PY + (size_t)b * GSTRIDE);
    for (int u = tid; u < 260; u += 256) py4[u] = pyg[u];
    __syncthreads();
    const float* pys = (const float*)py4;

    for (int i = 0; i < NNZ; ++i) {
        // ---- Phase A: proj + local abs-argmax (pad atoms 1025..1039 are 0)
        float best = -1.0f; int bidx = 0;
        for (int u = tid; u < 260; u += 256) {
            float4 p = py4[u];
#pragma unroll 4
            for (int j = 0; j < i; ++j) {
                const float4 g = *(const float4*)&rowsLds[j][4 * u];
                const float wj = wv[j];
                p.x -= wj * g.x; p.y -= wj * g.y; p.z -= wj * g.z; p.w -= wj * g.w;
            }
            float pv[4] = {fabsf(p.x), fabsf(p.y), fabsf(p.z), fabsf(p.w)};
#pragma unroll
            for (int k = 0; k < 4; ++k) {
                if (pv[k] > best) { best = pv[k]; bidx = 4 * u + k; }
            }
        }
        for (int off = 32; off; off >>= 1) {
            float ov = __shfl_xor(best, off);
            int   oi = __shfl_xor(bidx, off);
            if (ov > best || (ov == best && oi < bidx)) { best = ov; bidx = oi; }
        }
        if (lane == 0) { redV[wid] = best; redI[wid] = bidx; }
        __syncthreads();                                     // (1)

        // all threads compute the block winner (broadcast LDS reads, free)
        float bv_ = redV[0]; int bi_ = redI[0];
#pragma unroll
        for (int q = 1; q < 4; ++q) {
            if (redV[q] > bv_ || (redV[q] == bv_ && redI[q] < bi_)) {
                bv_ = redV[q]; bi_ = redI[q];
            }
        }
        const int sel = bi_;
        if (tid == 0) { selIdx[i] = sel; rhs[i] = pys[sel]; }

        // ---- Phase B: stage G[sel] -> rowsLds[i]; gather border entries
        const float* __restrict__ grow = G + (size_t)sel * GSTRIDE;
        for (int u = tid; u < 260; u += 256) {
            *(float4*)&rowsLds[i][4 * u] = *(const float4*)&grow[4 * u];
        }
        if (tid < i) bvv[tid] = G[(size_t)sel * GSTRIDE + selIdx[tid]];
        if (tid == i) sc_c = grow[sel];
        __syncthreads();                                     // (2)

        // ---- Phase C: wave 0: u = Ainv*b ; dinv ; beta
        if (wid == 0) {
            float uj = 0.0f;
            if (lane < i) {
#pragma unroll 4
                for (int m = 0; m < i; ++m) uj += Ainv[lane][m] * bvv[m];
                uv[lane] = uj;
            }
            float t = (lane < i) ? bvv[lane] * uj : 0.0f;
            float s = (lane < i) ? rhs[lane] * uj : 0.0f;
            for (int off = 32; off; off >>= 1) {
                t += __shfl_xor(t, off);
                s += __shfl_xor(s, off);
            }
            if (lane == 0) {
                const float dinv = 1.0f / (sc_c + REGL - t);
                sc_dinv = dinv;
                sc_beta = dinv * (rhs[i] - s);
            }
        }
        __syncthreads();                                     // (3)

        // ---- Phase D: w update + bordered inverse update
        const float beta = sc_beta, dinv = sc_dinv;
        if (tid < i) wv[tid] -= uv[tid] * beta;
        if (tid == i) wv[i] = beta;
        for (int e = tid; e < i * i; e += 256) {
            const int j = e / i, k = e - j * i;
            Ainv[j][k] += uv[j] * uv[k] * dinv;
        }
        if (tid < i) {
            const float v = -uv[tid] * dinv;
            Ainv[i][tid] = v;
            Ainv[tid][i] = v;
        }
        if (tid == 0) Ainv[i][i] = dinv;
        __syncthreads();                                     // (4)
    }

    if (tid < NNZ) {
        idxOut[b * NNZ + tid] = selIdx[tid];
        wOut[b * NNZ + tid] = wv[tid];
    }
}

// ---------------------------------------------------------------------------
// recon: out[b][l] = sum_a X[b][l][a]*W[b][a] + W[b][1024]
// W built dense in LDS with sequential last-wins scatter (matches .at[].set)
// ---------------------------------------------------------------------------
__global__ __launch_bounds__(256)
void recon_kernel(const float* __restrict__ X, const int* __restrict__ idxIn,
                  const float* __restrict__ wIn, float* __restrict__ out) {
    __shared__ float4 Wd4[260];          // 1040 floats
    const int b = blockIdx.x >> 3, chunk = blockIdx.x & 7;
    const int tid = threadIdx.x, lane = tid & 63, wid = tid >> 6;
    float* Wd = (float*)Wd4;
    for (int u = tid; u < 1040; u += 256) Wd[u] = 0.0f;
    __syncthreads();
    if (tid == 0) {
#pragma unroll
        for (int i = 0; i < NNZ; ++i) Wd[idxIn[b * NNZ + i]] = wIn[b * NNZ + i];
    }
    __syncthreads();
    const float wOne = Wd[1024];
    const float* Xb = X + (size_t)b * 1024 * 1024;

    for (int rr = wid; rr < 128; rr += 4) {
        const int r = chunk * 128 + rr;
        const float4* xr = (const float4*)(Xb + (size_t)r * 1024);
        float acc = 0.0f;
#pragma unroll
        for (int q = 0; q < 4; ++q) {
            float4 x = xr[q * 64 + lane];
            float4 w = Wd4[q * 64 + lane];
            acc += x.x * w.x + x.y * w.y + x.z * w.z + x.w * w.w;
        }
        for (int off = 32; off; off >>= 1) acc += __shfl_xor(acc, off);
        if (lane == 0) out[(size_t)b * 1024 + r] = acc + wOne;
    }
}

// ---------------------------------------------------------------------------
extern "C" void kernel_launch(void* const* d_in, const int* in_sizes, int n_in,
                              void* d_out, int out_size, void* d_ws, size_t ws_size,
                              hipStream_t stream) {
    const float* X = (const float*)d_in[0];
    const float* y = (const float*)d_in[1];
    float* out = (float*)d_out;
    float* ws = (float*)d_ws;

    // workspace layout (floats):
    //   split-K=4:  [4 x GELEMS partials][GELEMS G][64*GSTRIDE PY][w 2048][idx 2048]
    //   fallback:   [GELEMS G][64*GSTRIDE PY][w 2048][idx 2048]
    const size_t need4 = ((size_t)GELEMS * 5 + 64 * GSTRIDE + NBATCH * NNZ * 2 + 64) * sizeof(float);
    const bool split4 = (ws_size >= need4);

    float* G;
    if (split4) {
        float* Gp = ws;
        G = ws + (size_t)GELEMS * 4;
        gram_kernel<<<dim3(9, 9, 4), 256, 0, stream>>>(X, Gp, 256);
        combine_kernel<<<(GELEMS / 4 + 255) / 256, 256, 0, stream>>>(Gp, G);
    } else {
        G = ws;
        gram_kernel<<<dim3(9, 9, 1), 256, 0, stream>>>(X, G, 1024);
    }
    float* PY = G + (size_t)GELEMS;
    float* wOut = PY + (size_t)64 * GSTRIDE;
    int* idxOut = (int*)(wOut + NBATCH * NNZ);

    projy_kernel<<<dim3(17, 4), 256, 0, stream>>>(X, y, PY);
    omp_kernel<<<NBATCH, 256, 0, stream>>>(G, PY, idxOut, wOut);
    recon_kernel<<<NBATCH * 8, 256, 0, stream>>>(X, idxOut, wOut, out);
}